// Round 2
// baseline (590.370 us; speedup 1.0000x reference)
//
#include <hip/hip_runtime.h>
#include <hip/hip_bf16.h>
#include <math.h>

using bf16 = __hip_bfloat16;
typedef __bf16 bf16x8 __attribute__((ext_vector_type(8)));
typedef float  f32x4  __attribute__((ext_vector_type(4)));

static constexpr int Lq = 2048, Nb = 2, E = 1024, Hh = 16, Dd = 64, Ff = 4096;
static constexpr int MT = Lq * Nb;          // 4096 tokens
static constexpr int RS = Nb * E;           // 2048 elems per seq-position in (L,N,E)

__device__ __forceinline__ void async_lds16(const void* g, void* l) {
  __builtin_amdgcn_global_load_lds(
      (const __attribute__((address_space(1))) void*)g,
      (__attribute__((address_space(3))) void*)l, 16, 0, 0);
}
__device__ __forceinline__ bf16x8 ld8(const bf16* p) { return *(const bf16x8*)p; }

// ---------------------------------------------------------------------------
// f32 -> bf16 cast, float4 per thread
// ---------------------------------------------------------------------------
__global__ __launch_bounds__(256) void cvt_kernel(const float* __restrict__ in,
                                                  bf16* __restrict__ out, int n4) {
  int i = blockIdx.x * 256 + threadIdx.x;
  if (i < n4) {
    float4 v = ((const float4*)in)[i];
    bf16 o4[4] = {__float2bfloat16(v.x), __float2bfloat16(v.y),
                  __float2bfloat16(v.z), __float2bfloat16(v.w)};
    *(uint2*)(out + 4 * (size_t)i) = *(uint2*)o4;
  }
}

// ---------------------------------------------------------------------------
// GEMM: C[m][n] = sum_k A[m][k] * W[n][k]  (A,W bf16; fp32 accum)
// 128x128 tile, BK=32, 4 waves 2x2, each wave 64x64 via 4x4 of 16x16x32 MFMA.
// EPI 0: (acc+bias)*scale -> bf16 out
// EPI 1: acc+bias+res(f32) -> f32 out
// EPI 2: gelu(acc+bias) -> bf16 out
// ---------------------------------------------------------------------------
template <int EPI>
__global__ __launch_bounds__(256) void gemm_bt(
    const bf16* __restrict__ A, const bf16* __restrict__ W,
    const float* __restrict__ bias, int K, int Nld, float scale,
    const float* __restrict__ res, bf16* __restrict__ outb,
    float* __restrict__ outf) {
  __shared__ __align__(16) bf16 As[128 * 32];
  __shared__ __align__(16) bf16 Bs[128 * 32];
  const int tid = threadIdx.x;
  const int w = tid >> 6, lane = tid & 63;
  const int quad = lane >> 4, l16 = lane & 15;
  const int wm = (w >> 1) * 64, wn = (w & 1) * 64;
  const int m0 = blockIdx.y * 128, n0 = blockIdx.x * 128;

  f32x4 acc[4][4];
#pragma unroll
  for (int i = 0; i < 4; i++)
#pragma unroll
    for (int j = 0; j < 4; j++)
#pragma unroll
      for (int r = 0; r < 4; r++) acc[i][j][r] = 0.f;

  // staging: chunk c (16B = 8 bf16): row = c>>2, col = (c&3)*8; LDS dest = 16B*c
  const int c0 = w * 64 + lane;
  const int c1 = c0 + 256;
  const size_t arow0 = (size_t)(m0 + (c0 >> 2)), arow1 = (size_t)(m0 + (c1 >> 2));
  const size_t brow0 = (size_t)(n0 + (c0 >> 2)), brow1 = (size_t)(n0 + (c1 >> 2));
  const int col0 = (c0 & 3) * 8, col1 = (c1 & 3) * 8;
  bf16* ldsA0 = &As[(w * 64) * 8];
  bf16* ldsA1 = &As[(256 + w * 64) * 8];
  bf16* ldsB0 = &Bs[(w * 64) * 8];
  bf16* ldsB1 = &Bs[(256 + w * 64) * 8];

  const int nk = K >> 5;
  for (int kt = 0; kt < nk; ++kt) {
    const int k0 = kt * 32;
    async_lds16(A + arow0 * K + k0 + col0, ldsA0);
    async_lds16(A + arow1 * K + k0 + col1, ldsA1);
    async_lds16(W + brow0 * K + k0 + col0, ldsB0);
    async_lds16(W + brow1 * K + k0 + col1, ldsB1);
    __syncthreads();
    bf16x8 a[4], b[4];
#pragma unroll
    for (int i = 0; i < 4; i++) {
      a[i] = ld8(&As[(wm + i * 16 + l16) * 32 + quad * 8]);
      b[i] = ld8(&Bs[(wn + i * 16 + l16) * 32 + quad * 8]);
    }
#pragma unroll
    for (int i = 0; i < 4; i++)
#pragma unroll
      for (int j = 0; j < 4; j++)
        acc[i][j] = __builtin_amdgcn_mfma_f32_16x16x32_bf16(a[i], b[j], acc[i][j], 0, 0, 0);
    __syncthreads();
  }

#pragma unroll
  for (int i = 0; i < 4; i++) {
    const int mrow = m0 + wm + i * 16 + quad * 4;
#pragma unroll
    for (int j = 0; j < 4; j++) {
      const int ncol = n0 + wn + j * 16 + l16;
      const float bv = bias[ncol];
#pragma unroll
      for (int r = 0; r < 4; r++) {
        const size_t idx = (size_t)(mrow + r) * Nld + ncol;
        float v = (acc[i][j][r] + bv) * scale;
        if constexpr (EPI == 0) {
          outb[idx] = __float2bfloat16(v);
        } else if constexpr (EPI == 1) {
          outf[idx] = v + res[idx];
        } else {
          v = 0.5f * v * (1.f + erff(v * 0.70710678118f));
          outb[idx] = __float2bfloat16(v);
        }
      }
    }
  }
}

// ---------------------------------------------------------------------------
// LayerNorm over E=1024 per token (f32 in, bf16 out). One block per token.
// ---------------------------------------------------------------------------
__global__ __launch_bounds__(256) void ln_kernel(
    const float* __restrict__ x, const float* __restrict__ wgt,
    const float* __restrict__ bia, bf16* __restrict__ out) {
  const int t = blockIdx.x, tid = threadIdx.x;
  const size_t base = (size_t)t * E;
  float v4[4], s = 0.f, ss = 0.f;
#pragma unroll
  for (int i = 0; i < 4; i++) {
    float v = x[base + i * 256 + tid];
    v4[i] = v; s += v; ss += v * v;
  }
  for (int off = 32; off > 0; off >>= 1) {
    s += __shfl_down(s, off, 64);
    ss += __shfl_down(ss, off, 64);
  }
  __shared__ float rs[4], rss[4], mv[2];
  const int w = tid >> 6;
  if ((tid & 63) == 0) { rs[w] = s; rss[w] = ss; }
  __syncthreads();
  if (tid == 0) {
    float S = rs[0] + rs[1] + rs[2] + rs[3];
    float SS = rss[0] + rss[1] + rss[2] + rss[3];
    float mean = S * (1.f / E);
    float var = SS * (1.f / E) - mean * mean;
    mv[0] = mean; mv[1] = rsqrtf(var + 1e-5f);
  }
  __syncthreads();
  const float mean = mv[0], rstd = mv[1];
#pragma unroll
  for (int i = 0; i < 4; i++) {
    const int e = i * 256 + tid;
    float r = (v4[i] - mean) * rstd * wgt[e] + bia[e];
    out[base + e] = __float2bfloat16(r);
  }
}

// ---------------------------------------------------------------------------
// Flash attention: grid (32 q-tiles, 32 (n,h)), block 256 (4 waves).
// Q/K/V/O layout: [l*2048 + n*1024 + h*64 + d]; q pre-scaled by 1/8.
// Each wave owns 16 q-rows. Online softmax; P via LDS; V transposed in LDS.
// ---------------------------------------------------------------------------
__global__ __launch_bounds__(256) void attn_kernel(
    const bf16* __restrict__ Q, const bf16* __restrict__ K,
    const bf16* __restrict__ V, bf16* __restrict__ O) {
  constexpr int LDT = 72;  // padded LDS leading dim
  __shared__ __align__(16) bf16 Qs[64 * LDT], Ks[64 * LDT], Vt[64 * LDT], Ps[64 * LDT];
  const int tid = threadIdx.x;
  const int w = tid >> 6, lane = tid & 63, quad = lane >> 4, l16 = lane & 15;
  const int qt = blockIdx.x;
  const int hh = blockIdx.y;
  const int n = hh >> 4, h = hh & 15;
  const size_t hb = (size_t)n * E + h * Dd;

  for (int it = 0; it < 2; it++) {
    const int c = tid + it * 256;
    const int row = c >> 3, d0 = (c & 7) * 8;
    *(uint4*)&Qs[row * LDT + d0] =
        *(const uint4*)&Q[(size_t)(qt * 64 + row) * RS + hb + d0];
  }
  __syncthreads();

  bf16x8 aq[2];
#pragma unroll
  for (int kk = 0; kk < 2; kk++)
    aq[kk] = ld8(&Qs[(w * 16 + l16) * LDT + kk * 32 + quad * 8]);

  f32x4 o_acc[4];
#pragma unroll
  for (int nd = 0; nd < 4; nd++)
#pragma unroll
    for (int r = 0; r < 4; r++) o_acc[nd][r] = 0.f;
  float m_run[4], l_run[4];
#pragma unroll
  for (int r = 0; r < 4; r++) { m_run[r] = -1e30f; l_run[r] = 0.f; }

  for (int kt = 0; kt <= qt; ++kt) {
    for (int it = 0; it < 2; it++) {
      const int c = tid + it * 256;
      const int row = c >> 3, d0 = (c & 7) * 8;
      const size_t g = (size_t)(kt * 64 + row) * RS + hb + d0;
      *(uint4*)&Ks[row * LDT + d0] = *(const uint4*)&K[g];
      uint4 tv = *(const uint4*)&V[g];
      const bf16* tb = (const bf16*)&tv;
#pragma unroll
      for (int i = 0; i < 8; i++) Vt[(d0 + i) * LDT + row] = tb[i];
    }
    __syncthreads();

    f32x4 s[4];
#pragma unroll
    for (int ni = 0; ni < 4; ni++) {
#pragma unroll
      for (int r = 0; r < 4; r++) s[ni][r] = 0.f;
      s[ni] = __builtin_amdgcn_mfma_f32_16x16x32_bf16(
          aq[0], ld8(&Ks[(ni * 16 + l16) * LDT + quad * 8]), s[ni], 0, 0, 0);
      s[ni] = __builtin_amdgcn_mfma_f32_16x16x32_bf16(
          aq[1], ld8(&Ks[(ni * 16 + l16) * LDT + 32 + quad * 8]), s[ni], 0, 0, 0);
    }
    if (kt == qt) {  // causal mask on diagonal tile (matches reference -10000)
#pragma unroll
      for (int ni = 0; ni < 4; ni++) {
        const int kg = kt * 64 + ni * 16 + l16;
#pragma unroll
        for (int r = 0; r < 4; r++) {
          const int qg = qt * 64 + w * 16 + quad * 4 + r;
          if (kg > qg) s[ni][r] = -10000.0f;
        }
      }
    }
    float tmax[4], alpha[4], rsum[4];
#pragma unroll
    for (int r = 0; r < 4; r++) {
      tmax[r] = fmaxf(fmaxf(s[0][r], s[1][r]), fmaxf(s[2][r], s[3][r]));
      for (int off = 1; off < 16; off <<= 1)
        tmax[r] = fmaxf(tmax[r], __shfl_xor(tmax[r], off, 64));
      const float mnew = fmaxf(m_run[r], tmax[r]);
      alpha[r] = __expf(m_run[r] - mnew);
      m_run[r] = mnew;
    }
    float p[4][4];
#pragma unroll
    for (int r = 0; r < 4; r++) rsum[r] = 0.f;
#pragma unroll
    for (int ni = 0; ni < 4; ni++)
#pragma unroll
      for (int r = 0; r < 4; r++) {
        p[ni][r] = __expf(s[ni][r] - m_run[r]);
        rsum[r] += p[ni][r];
      }
#pragma unroll
    for (int r = 0; r < 4; r++) {
      for (int off = 1; off < 16; off <<= 1) rsum[r] += __shfl_xor(rsum[r], off, 64);
      l_run[r] = l_run[r] * alpha[r] + rsum[r];
    }
#pragma unroll
    for (int nd = 0; nd < 4; nd++)
#pragma unroll
      for (int r = 0; r < 4; r++) o_acc[nd][r] *= alpha[r];
#pragma unroll
    for (int ni = 0; ni < 4; ni++)
#pragma unroll
      for (int r = 0; r < 4; r++)
        Ps[(w * 16 + quad * 4 + r) * LDT + ni * 16 + l16] = __float2bfloat16(p[ni][r]);
    __syncthreads();

    bf16x8 ap0 = ld8(&Ps[(w * 16 + l16) * LDT + quad * 8]);
    bf16x8 ap1 = ld8(&Ps[(w * 16 + l16) * LDT + 32 + quad * 8]);
#pragma unroll
    for (int nd = 0; nd < 4; nd++) {
      o_acc[nd] = __builtin_amdgcn_mfma_f32_16x16x32_bf16(
          ap0, ld8(&Vt[(nd * 16 + l16) * LDT + quad * 8]), o_acc[nd], 0, 0, 0);
      o_acc[nd] = __builtin_amdgcn_mfma_f32_16x16x32_bf16(
          ap1, ld8(&Vt[(nd * 16 + l16) * LDT + 32 + quad * 8]), o_acc[nd], 0, 0, 0);
    }
    __syncthreads();
  }

#pragma unroll
  for (int nd = 0; nd < 4; nd++)
#pragma unroll
    for (int r = 0; r < 4; r++) {
      const int qg = qt * 64 + w * 16 + quad * 4 + r;
      const float inv_l = 1.f / fmaxf(l_run[r], 1e-20f);
      O[(size_t)qg * RS + hb + nd * 16 + l16] =
          __float2bfloat16(o_acc[nd][r] * inv_l);
    }
}

// ---------------------------------------------------------------------------
extern "C" void kernel_launch(void* const* d_in, const int* in_sizes, int n_in,
                              void* d_out, int out_size, void* d_ws, size_t ws_size,
                              hipStream_t stream) {
  const float* x    = (const float*)d_in[0];
  const float* ln1w = (const float*)d_in[1];
  const float* ln1b = (const float*)d_in[2];
  const float* wq   = (const float*)d_in[3];
  const float* bq   = (const float*)d_in[4];
  const float* wk   = (const float*)d_in[5];
  const float* bk   = (const float*)d_in[6];
  const float* wv   = (const float*)d_in[7];
  const float* bv   = (const float*)d_in[8];
  const float* wout = (const float*)d_in[9];
  const float* bout = (const float*)d_in[10];
  const float* ln2w = (const float*)d_in[11];
  const float* ln2b = (const float*)d_in[12];
  const float* fc1w = (const float*)d_in[13];
  const float* fc1b = (const float*)d_in[14];
  const float* fc2w = (const float*)d_in[15];
  const float* fc2b = (const float*)d_in[16];

  char* ws = (char*)d_ws;
  bf16* wqb   = (bf16*)(ws);                        // 2 MB
  bf16* wkb   = (bf16*)(ws + ((size_t)2 << 20));    // 2 MB
  bf16* wvb   = (bf16*)(ws + ((size_t)4 << 20));    // 2 MB
  bf16* woutb = (bf16*)(ws + ((size_t)6 << 20));    // 2 MB
  bf16* f1wb  = (bf16*)(ws + ((size_t)8 << 20));    // 8 MB
  bf16* f2wb  = (bf16*)(ws + ((size_t)16 << 20));   // 8 MB
  bf16* h1 = (bf16*)(ws + ((size_t)24 << 20));      // 8 MB (h2 reuses)
  bf16* q  = (bf16*)(ws + ((size_t)32 << 20));      // 8 MB
  bf16* k  = (bf16*)(ws + ((size_t)40 << 20));      // 8 MB
  bf16* v  = (bf16*)(ws + ((size_t)48 << 20));      // 8 MB
  bf16* o  = (bf16*)(ws + ((size_t)56 << 20));      // 8 MB
  float* x1 = (float*)(ws + ((size_t)64 << 20));    // 16 MB f32
  bf16* f1 = q;                                     // 32 MB (reuses q,k,v,o)
  bf16* h2 = h1;                                    // reuses h1
  float* outp = (float*)d_out;

  const int nE2 = E * E / 4, nEF = E * Ff / 4;      // float4 counts
  cvt_kernel<<<nE2 / 256, 256, 0, stream>>>(wq, wqb, nE2);
  cvt_kernel<<<nE2 / 256, 256, 0, stream>>>(wk, wkb, nE2);
  cvt_kernel<<<nE2 / 256, 256, 0, stream>>>(wv, wvb, nE2);
  cvt_kernel<<<nE2 / 256, 256, 0, stream>>>(wout, woutb, nE2);
  cvt_kernel<<<nEF / 256, 256, 0, stream>>>(fc1w, f1wb, nEF);
  cvt_kernel<<<nEF / 256, 256, 0, stream>>>(fc2w, f2wb, nEF);

  ln_kernel<<<MT, 256, 0, stream>>>(x, ln1w, ln1b, h1);

  dim3 gE(E / 128, MT / 128);    // (8,32)
  dim3 gF(Ff / 128, MT / 128);   // (32,32)
  gemm_bt<0><<<gE, 256, 0, stream>>>(h1, wqb, bq, E, E, 0.125f, nullptr, q, nullptr);
  gemm_bt<0><<<gE, 256, 0, stream>>>(h1, wkb, bk, E, E, 1.f, nullptr, k, nullptr);
  gemm_bt<0><<<gE, 256, 0, stream>>>(h1, wvb, bv, E, E, 1.f, nullptr, v, nullptr);

  attn_kernel<<<dim3(Lq / 64, Nb * Hh), 256, 0, stream>>>(q, k, v, o);

  gemm_bt<1><<<gE, 256, 0, stream>>>(o, woutb, bout, E, E, 1.f, x, nullptr, x1);
  ln_kernel<<<MT, 256, 0, stream>>>(x1, ln2w, ln2b, h2);
  gemm_bt<2><<<gF, 256, 0, stream>>>(h2, f1wb, fc1b, E, Ff, 1.f, nullptr, f1, nullptr);
  gemm_bt<1><<<gE, 256, 0, stream>>>(f1, f2wb, fc2b, Ff, E, 1.f, x1, nullptr, outp);
}

// Round 3
// 465.626 us; speedup vs baseline: 1.2679x; 1.2679x over previous
//
#include <hip/hip_runtime.h>
#include <hip/hip_bf16.h>
#include <math.h>

using bf16 = __hip_bfloat16;
typedef __bf16 bf16x8 __attribute__((ext_vector_type(8)));
typedef short  short4v __attribute__((ext_vector_type(4)));
typedef float  f32x4  __attribute__((ext_vector_type(4)));

static constexpr int Lq = 2048, Nb = 2, E = 1024, Hh = 16, Dd = 64, Ff = 4096;
static constexpr int MT = Lq * Nb;          // 4096 tokens
static constexpr int QKVLD = 3 * E;         // 3072: fused qkv row stride (per token)
static constexpr int LDL = 2 * QKVLD;       // 6144: stride per seq-step l in qkv buf

__device__ __forceinline__ void async_lds16(const void* g, void* l) {
  __builtin_amdgcn_global_load_lds(
      (const __attribute__((address_space(1))) void*)g,
      (__attribute__((address_space(3))) void*)l, 16, 0, 0);
}
__device__ __forceinline__ bf16x8 ld8(const bf16* p) { return *(const bf16x8*)p; }
__device__ __forceinline__ short bfbits(float x) {
  bf16 t = __float2bfloat16(x);
  return *(short*)&t;
}

// ---------------------------------------------------------------------------
// f32 -> bf16 cast, float4 per thread
// ---------------------------------------------------------------------------
__global__ __launch_bounds__(256) void cvt_kernel(const float* __restrict__ in,
                                                  bf16* __restrict__ out, int n4) {
  int i = blockIdx.x * 256 + threadIdx.x;
  if (i < n4) {
    float4 v = ((const float4*)in)[i];
    bf16 o4[4] = {__float2bfloat16(v.x), __float2bfloat16(v.y),
                  __float2bfloat16(v.z), __float2bfloat16(v.w)};
    *(uint2*)(out + 4 * (size_t)i) = *(uint2*)o4;
  }
}

// ---------------------------------------------------------------------------
// GEMM: C[m][n] = sum_k A[m][k] * W[n][k]  (A,W bf16; fp32 accum)
// 128x128 tile, BK=32, 4 waves 2x2, each wave 64x64 via 4x4 of 16x16x32 MFMA.
// Bias: if b3 != null, 3-way concat select (QKV). Scale qscale for ncol<scut.
// EPI 0: (acc+bias)*scale -> bf16 out
// EPI 1: acc+bias+res(f32) -> f32 out
// EPI 2: gelu(acc+bias) -> bf16 out
// EPI 3: acc+bias+res(f32) -> f32 written to outf AND final (same thing)
// ---------------------------------------------------------------------------
template <int EPI>
__global__ __launch_bounds__(256) void gemm_bt(
    const bf16* __restrict__ A, const bf16* __restrict__ W,
    const float* __restrict__ b1, const float* __restrict__ b2,
    const float* __restrict__ b3, int K, int Nld, float qscale, int scut,
    const float* __restrict__ res, bf16* __restrict__ outb,
    float* __restrict__ outf) {
  __shared__ __align__(16) bf16 As[128 * 32];
  __shared__ __align__(16) bf16 Bs[128 * 32];
  const int tid = threadIdx.x;
  const int w = tid >> 6, lane = tid & 63;
  const int quad = lane >> 4, l16 = lane & 15;
  const int wm = (w >> 1) * 64, wn = (w & 1) * 64;
  const int m0 = blockIdx.y * 128, n0 = blockIdx.x * 128;

  f32x4 acc[4][4];
#pragma unroll
  for (int i = 0; i < 4; i++)
#pragma unroll
    for (int j = 0; j < 4; j++)
#pragma unroll
      for (int r = 0; r < 4; r++) acc[i][j][r] = 0.f;

  const int c0 = w * 64 + lane;
  const int c1 = c0 + 256;
  const size_t arow0 = (size_t)(m0 + (c0 >> 2)), arow1 = (size_t)(m0 + (c1 >> 2));
  const size_t brow0 = (size_t)(n0 + (c0 >> 2)), brow1 = (size_t)(n0 + (c1 >> 2));
  const int col0 = (c0 & 3) * 8, col1 = (c1 & 3) * 8;
  bf16* ldsA0 = &As[(w * 64) * 8];
  bf16* ldsA1 = &As[(256 + w * 64) * 8];
  bf16* ldsB0 = &Bs[(w * 64) * 8];
  bf16* ldsB1 = &Bs[(256 + w * 64) * 8];

  const int nk = K >> 5;
  for (int kt = 0; kt < nk; ++kt) {
    const int k0 = kt * 32;
    async_lds16(A + arow0 * K + k0 + col0, ldsA0);
    async_lds16(A + arow1 * K + k0 + col1, ldsA1);
    async_lds16(W + brow0 * K + k0 + col0, ldsB0);
    async_lds16(W + brow1 * K + k0 + col1, ldsB1);
    __syncthreads();
    bf16x8 a[4], b[4];
#pragma unroll
    for (int i = 0; i < 4; i++) {
      a[i] = ld8(&As[(wm + i * 16 + l16) * 32 + quad * 8]);
      b[i] = ld8(&Bs[(wn + i * 16 + l16) * 32 + quad * 8]);
    }
#pragma unroll
    for (int i = 0; i < 4; i++)
#pragma unroll
      for (int j = 0; j < 4; j++)
        acc[i][j] = __builtin_amdgcn_mfma_f32_16x16x32_bf16(a[i], b[j], acc[i][j], 0, 0, 0);
    __syncthreads();
  }

#pragma unroll
  for (int i = 0; i < 4; i++) {
    const int mrow = m0 + wm + i * 16 + quad * 4;
#pragma unroll
    for (int j = 0; j < 4; j++) {
      const int ncol = n0 + wn + j * 16 + l16;
      float bv;
      if (b3 != nullptr) {
        bv = (ncol < 1024) ? b1[ncol]
             : (ncol < 2048) ? b2[ncol - 1024] : b3[ncol - 2048];
      } else {
        bv = b1[ncol];
      }
      const float sc = (ncol < scut) ? qscale : 1.0f;
#pragma unroll
      for (int r = 0; r < 4; r++) {
        const size_t idx = (size_t)(mrow + r) * Nld + ncol;
        float v = (acc[i][j][r] + bv) * sc;
        if constexpr (EPI == 0) {
          outb[idx] = __float2bfloat16(v);
        } else if constexpr (EPI == 1) {
          outf[idx] = v + res[idx];
        } else {
          v = 0.5f * v * (1.f + erff(v * 0.70710678118f));
          outb[idx] = __float2bfloat16(v);
        }
      }
    }
  }
}

// ---------------------------------------------------------------------------
// LayerNorm over E=1024 per token (f32 in, bf16 out). One block per token.
// ---------------------------------------------------------------------------
__global__ __launch_bounds__(256) void ln_kernel(
    const float* __restrict__ x, const float* __restrict__ wgt,
    const float* __restrict__ bia, bf16* __restrict__ out) {
  const int t = blockIdx.x, tid = threadIdx.x;
  const size_t base = (size_t)t * E;
  float v4[4], s = 0.f, ss = 0.f;
#pragma unroll
  for (int i = 0; i < 4; i++) {
    float v = x[base + i * 256 + tid];
    v4[i] = v; s += v; ss += v * v;
  }
  for (int off = 32; off > 0; off >>= 1) {
    s += __shfl_down(s, off, 64);
    ss += __shfl_down(ss, off, 64);
  }
  __shared__ float rs[4], rss[4], mv[2];
  const int w = tid >> 6;
  if ((tid & 63) == 0) { rs[w] = s; rss[w] = ss; }
  __syncthreads();
  if (tid == 0) {
    float S = rs[0] + rs[1] + rs[2] + rs[3];
    float SS = rss[0] + rss[1] + rss[2] + rss[3];
    float mean = S * (1.f / E);
    float var = SS * (1.f / E) - mean * mean;
    mv[0] = mean; mv[1] = rsqrtf(var + 1e-5f);
  }
  __syncthreads();
  const float mean = mv[0], rstd = mv[1];
#pragma unroll
  for (int i = 0; i < 4; i++) {
    const int e = i * 256 + tid;
    float r = (v4[i] - mean) * rstd * wgt[e] + bia[e];
    out[base + e] = __float2bfloat16(r);
  }
}

// ---------------------------------------------------------------------------
// Flash attention v2 (S-transposed): grid (16 pairs, 32 (n,h)), 256 thr.
// Each block handles q-tiles {31-pid, pid} (uniform 33 k-iters).
// S^T = K·Q^T (16x16x32): lane owns q=l16 -> 2-shuffle softmax, per-lane m/l.
// O^T = V^T·P^T (16x16x16_1k): S^T C-regs feed B-operand directly (no P LDS).
// Only V staged in LDS (transposed, double-buffered); K/Q read from global.
// ---------------------------------------------------------------------------
__global__ __launch_bounds__(256) void attn_kernel(
    const bf16* __restrict__ QKV, bf16* __restrict__ O) {
  constexpr int LDT = 72;
  __shared__ __align__(16) bf16 Vt[2][64 * LDT];
  const int tid = threadIdx.x;
  const int w = tid >> 6, lane = tid & 63, quad = lane >> 4, l16 = lane & 15;
  const int pid = blockIdx.x;   // 0..15
  const int hh = blockIdx.y;    // 0..31
  const int n = hh >> 4, h = hh & 15;
  const int hb = n * QKVLD + h * Dd;
  const bf16* Qp = QKV + hb;
  const bf16* Kp = QKV + hb + E;
  const bf16* Vp = QKV + hb + 2 * E;

  // V staging mapping: two 16B chunks per thread
  const int vrow0 = tid >> 3, vd0 = (tid & 7) * 8;
  const int vrow1 = (tid + 256) >> 3, vd1 = (tid & 7) * 8;

  for (int half = 0; half < 2; ++half) {
    const int qt = (half == 0) ? (31 - pid) : pid;
    __syncthreads();  // protect Vt reuse across halves

    const int ql = qt * 64 + w * 16 + l16;  // this lane's q (sequence pos)
    const bf16x8 aq0 = ld8(Qp + (size_t)ql * LDL + quad * 8);
    const bf16x8 aq1 = ld8(Qp + (size_t)ql * LDL + 32 + quad * 8);

    f32x4 o_acc[4];
#pragma unroll
    for (int d = 0; d < 4; d++)
#pragma unroll
      for (int r = 0; r < 4; r++) o_acc[d][r] = 0.f;
    float m_run = -1e30f, l_run = 0.f;

    // preload kt = 0
    bf16x8 kc[4][2];
    uint4 vc0, vc1;
#pragma unroll
    for (int ks = 0; ks < 4; ks++)
#pragma unroll
      for (int c = 0; c < 2; c++)
        kc[ks][c] = ld8(Kp + (size_t)(ks * 16 + l16) * LDL + c * 32 + quad * 8);
    vc0 = *(const uint4*)(Vp + (size_t)vrow0 * LDL + vd0);
    vc1 = *(const uint4*)(Vp + (size_t)vrow1 * LDL + vd1);

    for (int kt = 0; kt <= qt; ++kt) {
      bf16* vb = Vt[kt & 1];
      {  // write prefetched V (transposed)
        const bf16* t0 = (const bf16*)&vc0;
        const bf16* t1 = (const bf16*)&vc1;
#pragma unroll
        for (int i = 0; i < 8; i++) vb[(vd0 + i) * LDT + vrow0] = t0[i];
#pragma unroll
        for (int i = 0; i < 8; i++) vb[(vd1 + i) * LDT + vrow1] = t1[i];
      }
      __syncthreads();

      // S^T = K · Q^T   (A = K rows m=k, B = Q^T; D col = q = l16)
      f32x4 s[4];
#pragma unroll
      for (int ks = 0; ks < 4; ks++) {
#pragma unroll
        for (int r = 0; r < 4; r++) s[ks][r] = 0.f;
        s[ks] = __builtin_amdgcn_mfma_f32_16x16x32_bf16(kc[ks][0], aq0, s[ks], 0, 0, 0);
        s[ks] = __builtin_amdgcn_mfma_f32_16x16x32_bf16(kc[ks][1], aq1, s[ks], 0, 0, 0);
      }

      // prefetch kt+1 K and V into registers (overlaps with softmax+PV)
      if (kt < qt) {
        const size_t kb = (size_t)(kt + 1) * 64;
#pragma unroll
        for (int ks = 0; ks < 4; ks++)
#pragma unroll
          for (int c = 0; c < 2; c++)
            kc[ks][c] = ld8(Kp + (kb + ks * 16 + l16) * LDL + c * 32 + quad * 8);
        vc0 = *(const uint4*)(Vp + (kb + vrow0) * LDL + vd0);
        vc1 = *(const uint4*)(Vp + (kb + vrow1) * LDL + vd1);
      }

      if (kt == qt) {  // causal mask on diagonal tile
#pragma unroll
        for (int ks = 0; ks < 4; ks++) {
#pragma unroll
          for (int r = 0; r < 4; r++) {
            const int kg = kt * 64 + ks * 16 + quad * 4 + r;
            if (kg > ql) s[ks][r] = -10000.0f;
          }
        }
      }

      // online softmax: lane owns q=l16; reduce over 16 in-lane + 2 shuffles
      float tmax = s[0][0];
#pragma unroll
      for (int ks = 0; ks < 4; ks++)
#pragma unroll
        for (int r = 0; r < 4; r++) tmax = fmaxf(tmax, s[ks][r]);
      tmax = fmaxf(tmax, __shfl_xor(tmax, 16, 64));
      tmax = fmaxf(tmax, __shfl_xor(tmax, 32, 64));
      const float mnew = fmaxf(m_run, tmax);
      const float alpha = __expf(m_run - mnew);
      m_run = mnew;
      float rsum = 0.f;
      short4v pf[4];
#pragma unroll
      for (int ks = 0; ks < 4; ks++) {
#pragma unroll
        for (int r = 0; r < 4; r++) {
          const float pv = __expf(s[ks][r] - mnew);
          rsum += pv;
          pf[ks][r] = bfbits(pv);
        }
      }
      rsum += __shfl_xor(rsum, 16, 64);
      rsum += __shfl_xor(rsum, 32, 64);
      l_run = l_run * alpha + rsum;
#pragma unroll
      for (int d = 0; d < 4; d++)
#pragma unroll
        for (int r = 0; r < 4; r++) o_acc[d][r] *= alpha;

      // O^T += V^T · P^T  (A = V^T from Vt LDS, B = P^T = S^T regs)
#pragma unroll
      for (int d = 0; d < 4; d++) {
#pragma unroll
        for (int ks = 0; ks < 4; ks++) {
          const short4v av =
              *(const short4v*)&vb[(d * 16 + l16) * LDT + ks * 16 + quad * 4];
          o_acc[d] = __builtin_amdgcn_mfma_f32_16x16x16bf16_1k(av, pf[ks], o_acc[d], 0, 0, 0);
        }
      }
    }

    // epilogue: lane q = l16 -> row ql; d = dsub*16 + quad*4 + r
    const float inv_l = 1.f / fmaxf(l_run, 1e-20f);
    const size_t obase = (size_t)ql * (Nb * E) + (size_t)n * E + h * Dd;
#pragma unroll
    for (int d = 0; d < 4; d++)
#pragma unroll
      for (int r = 0; r < 4; r++)
        O[obase + d * 16 + quad * 4 + r] = __float2bfloat16(o_acc[d][r] * inv_l);
  }
}

// ---------------------------------------------------------------------------
extern "C" void kernel_launch(void* const* d_in, const int* in_sizes, int n_in,
                              void* d_out, int out_size, void* d_ws, size_t ws_size,
                              hipStream_t stream) {
  const float* x    = (const float*)d_in[0];
  const float* ln1w = (const float*)d_in[1];
  const float* ln1b = (const float*)d_in[2];
  const float* wq   = (const float*)d_in[3];
  const float* bq   = (const float*)d_in[4];
  const float* wk   = (const float*)d_in[5];
  const float* bk   = (const float*)d_in[6];
  const float* wv   = (const float*)d_in[7];
  const float* bv   = (const float*)d_in[8];
  const float* wout = (const float*)d_in[9];
  const float* bout = (const float*)d_in[10];
  const float* ln2w = (const float*)d_in[11];
  const float* ln2b = (const float*)d_in[12];
  const float* fc1w = (const float*)d_in[13];
  const float* fc1b = (const float*)d_in[14];
  const float* fc2w = (const float*)d_in[15];
  const float* fc2b = (const float*)d_in[16];

  char* ws = (char*)d_ws;
  bf16* wqkvb = (bf16*)(ws);                        // 6 MB: [wq;wk;wv] rows
  bf16* woutb = (bf16*)(ws + ((size_t)6 << 20));    // 2 MB
  bf16* f1wb  = (bf16*)(ws + ((size_t)8 << 20));    // 8 MB
  bf16* f2wb  = (bf16*)(ws + ((size_t)16 << 20));   // 8 MB
  bf16* h1    = (bf16*)(ws + ((size_t)24 << 20));   // 8 MB (h2 reuses)
  bf16* qkv   = (bf16*)(ws + ((size_t)32 << 20));   // 24 MB [4096][3072]
  bf16* o     = (bf16*)(ws + ((size_t)56 << 20));   // 8 MB
  float* x1   = (float*)(ws + ((size_t)64 << 20));  // 16 MB f32
  bf16* f1    = (bf16*)(ws + ((size_t)32 << 20));   // 32 MB (reuses qkv,o)
  bf16* h2    = h1;
  float* outp = (float*)d_out;

  const int nE2 = E * E / 4, nEF = E * Ff / 4;
  cvt_kernel<<<nE2 / 256, 256, 0, stream>>>(wq, wqkvb, nE2);
  cvt_kernel<<<nE2 / 256, 256, 0, stream>>>(wk, wqkvb + (size_t)E * E, nE2);
  cvt_kernel<<<nE2 / 256, 256, 0, stream>>>(wv, wqkvb + (size_t)2 * E * E, nE2);
  cvt_kernel<<<nE2 / 256, 256, 0, stream>>>(wout, woutb, nE2);
  cvt_kernel<<<nEF / 256, 256, 0, stream>>>(fc1w, f1wb, nEF);
  cvt_kernel<<<nEF / 256, 256, 0, stream>>>(fc2w, f2wb, nEF);

  ln_kernel<<<MT, 256, 0, stream>>>(x, ln1w, ln1b, h1);

  dim3 gQKV(QKVLD / 128, MT / 128);  // (24,32)
  dim3 gE(E / 128, MT / 128);        // (8,32)
  dim3 gF(Ff / 128, MT / 128);       // (32,32)

  gemm_bt<0><<<gQKV, 256, 0, stream>>>(h1, wqkvb, bq, bk, bv, E, QKVLD,
                                       0.125f, 1024, nullptr, qkv, nullptr);

  attn_kernel<<<dim3(16, Nb * Hh), 256, 0, stream>>>(qkv, o);

  gemm_bt<1><<<gE, 256, 0, stream>>>(o, woutb, bout, nullptr, nullptr, E, E,
                                     1.f, 0, x, nullptr, x1);
  ln_kernel<<<MT, 256, 0, stream>>>(x1, ln2w, ln2b, h2);
  gemm_bt<2><<<gF, 256, 0, stream>>>(h2, f1wb, fc1b, nullptr, nullptr, E, Ff,
                                     1.f, 0, nullptr, f1, nullptr);
  gemm_bt<1><<<gE, 256, 0, stream>>>(f1, f2wb, fc2b, nullptr, nullptr, Ff, E,
                                     1.f, 0, x1, nullptr, outp);
}

// Round 4
// 428.514 us; speedup vs baseline: 1.3777x; 1.0866x over previous
//
#include <hip/hip_runtime.h>
#include <hip/hip_bf16.h>
#include <math.h>

using bf16 = __hip_bfloat16;
typedef __bf16 bf16x8 __attribute__((ext_vector_type(8)));
typedef short  short4v __attribute__((ext_vector_type(4)));
typedef float  f32x4  __attribute__((ext_vector_type(4)));

static constexpr int Lq = 2048, Nb = 2, E = 1024, Hh = 16, Dd = 64, Ff = 4096;
static constexpr int MT = Lq * Nb;          // 4096 tokens
static constexpr int QKVLD = 3 * E;         // 3072: fused qkv row stride (per token)
static constexpr int LDL = 2 * QKVLD;       // 6144: stride per seq-step l in qkv buf

__device__ __forceinline__ void async_lds16(const void* g, void* l) {
  __builtin_amdgcn_global_load_lds(
      (const __attribute__((address_space(1))) void*)g,
      (__attribute__((address_space(3))) void*)l, 16, 0, 0);
}
__device__ __forceinline__ bf16x8 ld8(const bf16* p) { return *(const bf16x8*)p; }
__device__ __forceinline__ short bfbits(float x) {
  bf16 t = __float2bfloat16(x);
  return *(short*)&t;
}

// ---------------------------------------------------------------------------
// Fused f32 -> bf16 cast of all 6 weight matrices in ONE dispatch.
// Region map (float4 units): [0,256K) wq | [256K,512K) wk | [512K,768K) wv |
// [768K,1M) wout | [1M,2M) fc1w | [2M,3M) fc2w
// ---------------------------------------------------------------------------
__global__ __launch_bounds__(256) void cvt_all_kernel(
    const float* __restrict__ wq, const float* __restrict__ wk,
    const float* __restrict__ wv, const float* __restrict__ wout,
    const float* __restrict__ fc1w, const float* __restrict__ fc2w,
    bf16* __restrict__ wqkvb, bf16* __restrict__ woutb,
    bf16* __restrict__ f1wb, bf16* __restrict__ f2wb) {
  const int i = blockIdx.x * 256 + threadIdx.x;
  const float* src;
  bf16* dst;
  size_t off;
  if (i < 786432) {            // qkv: three E*E blocks concat in wqkvb
    const int r = i >> 18;     // 0,1,2
    off = (size_t)(i & 262143);
    src = (r == 0) ? wq : (r == 1) ? wk : wv;
    dst = wqkvb + (size_t)r * (E * E);
  } else if (i < 1048576) {
    off = (size_t)(i - 786432); src = wout; dst = woutb;
  } else if (i < 2097152) {
    off = (size_t)(i - 1048576); src = fc1w; dst = f1wb;
  } else {
    off = (size_t)(i - 2097152); src = fc2w; dst = f2wb;
  }
  float4 v = ((const float4*)src)[off];
  bf16 o4[4] = {__float2bfloat16(v.x), __float2bfloat16(v.y),
                __float2bfloat16(v.z), __float2bfloat16(v.w)};
  *(uint2*)(dst + 4 * off) = *(uint2*)o4;
}

// ---------------------------------------------------------------------------
// GEMM: C[m][n] = sum_k A[m][k] * W[n][k]  (A,W bf16; fp32 accum)
// 128x128 tile, BK=32, 4 waves 2x2, each wave 64x64 via 4x4 of 16x16x32 MFMA.
// Klen = K-loop length (per z-chunk); Kstride = row stride of A and W.
// blockIdx.z selects K-chunk (koff = z*Klen); EPI 3 writes bf16 partial at
// z * MT*E (split-K), no bias.
// EPI 0: (acc+bias)*scale -> bf16 (3-way concat bias select if b3)
// EPI 1: acc+bias+res(f32) -> f32
// EPI 2: gelu(acc+bias) -> bf16
// EPI 3: acc -> bf16 partial
// ---------------------------------------------------------------------------
template <int EPI>
__global__ __launch_bounds__(256) void gemm_bt(
    const bf16* __restrict__ A, const bf16* __restrict__ W,
    const float* __restrict__ b1, const float* __restrict__ b2,
    const float* __restrict__ b3, int Klen, int Kstride, int Nld,
    float qscale, int scut, const float* __restrict__ res,
    bf16* __restrict__ outb, float* __restrict__ outf) {
  __shared__ __align__(16) bf16 As[128 * 32];
  __shared__ __align__(16) bf16 Bs[128 * 32];
  const int tid = threadIdx.x;
  const int w = tid >> 6, lane = tid & 63;
  const int quad = lane >> 4, l16 = lane & 15;
  const int wm = (w >> 1) * 64, wn = (w & 1) * 64;
  const int m0 = blockIdx.y * 128, n0 = blockIdx.x * 128;
  const int koff = blockIdx.z * Klen;

  f32x4 acc[4][4];
#pragma unroll
  for (int i = 0; i < 4; i++)
#pragma unroll
    for (int j = 0; j < 4; j++)
#pragma unroll
      for (int r = 0; r < 4; r++) acc[i][j][r] = 0.f;

  const int c0 = w * 64 + lane;
  const int c1 = c0 + 256;
  const size_t arow0 = (size_t)(m0 + (c0 >> 2)), arow1 = (size_t)(m0 + (c1 >> 2));
  const size_t brow0 = (size_t)(n0 + (c0 >> 2)), brow1 = (size_t)(n0 + (c1 >> 2));
  const int col0 = (c0 & 3) * 8, col1 = (c1 & 3) * 8;
  bf16* ldsA0 = &As[(w * 64) * 8];
  bf16* ldsA1 = &As[(256 + w * 64) * 8];
  bf16* ldsB0 = &Bs[(w * 64) * 8];
  bf16* ldsB1 = &Bs[(256 + w * 64) * 8];

  const int nk = Klen >> 5;
  for (int kt = 0; kt < nk; ++kt) {
    const int k0 = koff + kt * 32;
    async_lds16(A + arow0 * Kstride + k0 + col0, ldsA0);
    async_lds16(A + arow1 * Kstride + k0 + col1, ldsA1);
    async_lds16(W + brow0 * Kstride + k0 + col0, ldsB0);
    async_lds16(W + brow1 * Kstride + k0 + col1, ldsB1);
    __syncthreads();
    bf16x8 a[4], b[4];
#pragma unroll
    for (int i = 0; i < 4; i++) {
      a[i] = ld8(&As[(wm + i * 16 + l16) * 32 + quad * 8]);
      b[i] = ld8(&Bs[(wn + i * 16 + l16) * 32 + quad * 8]);
    }
#pragma unroll
    for (int i = 0; i < 4; i++)
#pragma unroll
      for (int j = 0; j < 4; j++)
        acc[i][j] = __builtin_amdgcn_mfma_f32_16x16x32_bf16(a[i], b[j], acc[i][j], 0, 0, 0);
    __syncthreads();
  }

  const size_t zoff = (EPI == 3) ? (size_t)blockIdx.z * ((size_t)MT * E) : 0;
#pragma unroll
  for (int i = 0; i < 4; i++) {
    const int mrow = m0 + wm + i * 16 + quad * 4;
#pragma unroll
    for (int j = 0; j < 4; j++) {
      const int ncol = n0 + wn + j * 16 + l16;
      float bv = 0.f;
      if constexpr (EPI != 3) {
        if (b3 != nullptr) {
          bv = (ncol < 1024) ? b1[ncol]
               : (ncol < 2048) ? b2[ncol - 1024] : b3[ncol - 2048];
        } else {
          bv = b1[ncol];
        }
      }
      const float sc = (ncol < scut) ? qscale : 1.0f;
#pragma unroll
      for (int r = 0; r < 4; r++) {
        const size_t idx = (size_t)(mrow + r) * Nld + ncol;
        float v = (acc[i][j][r] + bv) * sc;
        if constexpr (EPI == 0) {
          outb[idx] = __float2bfloat16(v);
        } else if constexpr (EPI == 1) {
          outf[idx] = v + res[idx];
        } else if constexpr (EPI == 2) {
          v = 0.5f * v * (1.f + erff(v * 0.70710678118f));
          outb[idx] = __float2bfloat16(v);
        } else {
          outb[zoff + idx] = __float2bfloat16(v);
        }
      }
    }
  }
}

// ---------------------------------------------------------------------------
// Split-K reduce: out[i] = P0[i] + P1[i] + bias[col] + res[i]   (f32 out)
// ---------------------------------------------------------------------------
__global__ __launch_bounds__(256) void reduce2_kernel(
    const bf16* __restrict__ P, const float* __restrict__ bias,
    const float* __restrict__ res, float* __restrict__ out) {
  const int i = blockIdx.x * 256 + threadIdx.x;  // float4 index
  const size_t e0 = (size_t)i * 4;
  const int col = (int)(e0 & (E - 1));
  uint2 u0 = *(const uint2*)(P + e0);
  uint2 u1 = *(const uint2*)(P + (size_t)MT * E + e0);
  const bf16* p0 = (const bf16*)&u0;
  const bf16* p1 = (const bf16*)&u1;
  float4 b = *(const float4*)(bias + col);
  float4 r = *(const float4*)(res + e0);
  float4 o;
  o.x = (float)p0[0] + (float)p1[0] + b.x + r.x;
  o.y = (float)p0[1] + (float)p1[1] + b.y + r.y;
  o.z = (float)p0[2] + (float)p1[2] + b.z + r.z;
  o.w = (float)p0[3] + (float)p1[3] + b.w + r.w;
  *(float4*)(out + e0) = o;
}

// ---------------------------------------------------------------------------
// LayerNorm over E=1024 per token (f32 in, bf16 out). One block per token.
// ---------------------------------------------------------------------------
__global__ __launch_bounds__(256) void ln_kernel(
    const float* __restrict__ x, const float* __restrict__ wgt,
    const float* __restrict__ bia, bf16* __restrict__ out) {
  const int t = blockIdx.x, tid = threadIdx.x;
  const size_t base = (size_t)t * E;
  float v4[4], s = 0.f, ss = 0.f;
#pragma unroll
  for (int i = 0; i < 4; i++) {
    float v = x[base + i * 256 + tid];
    v4[i] = v; s += v; ss += v * v;
  }
  for (int off = 32; off > 0; off >>= 1) {
    s += __shfl_down(s, off, 64);
    ss += __shfl_down(ss, off, 64);
  }
  __shared__ float rs[4], rss[4], mv[2];
  const int w = tid >> 6;
  if ((tid & 63) == 0) { rs[w] = s; rss[w] = ss; }
  __syncthreads();
  if (tid == 0) {
    float S = rs[0] + rs[1] + rs[2] + rs[3];
    float SS = rss[0] + rss[1] + rss[2] + rss[3];
    float mean = S * (1.f / E);
    float var = SS * (1.f / E) - mean * mean;
    mv[0] = mean; mv[1] = rsqrtf(var + 1e-5f);
  }
  __syncthreads();
  const float mean = mv[0], rstd = mv[1];
#pragma unroll
  for (int i = 0; i < 4; i++) {
    const int e = i * 256 + tid;
    float r = (v4[i] - mean) * rstd * wgt[e] + bia[e];
    out[base + e] = __float2bfloat16(r);
  }
}

// ---------------------------------------------------------------------------
// Flash attention v2 (S-transposed): grid (16 pairs, 32 (n,h)), 256 thr.
// Each block handles q-tiles {31-pid, pid} (uniform 33 k-iters).
// S^T = K·Q^T (16x16x32): lane owns q=l16 -> 2-shuffle softmax, per-lane m/l.
// O^T = V^T·P^T (16x16x16_1k): S^T C-regs feed B-operand directly (no P LDS).
// Only V staged in LDS (transposed, double-buffered); K/Q read from global.
// ---------------------------------------------------------------------------
__global__ __launch_bounds__(256) void attn_kernel(
    const bf16* __restrict__ QKV, bf16* __restrict__ O) {
  constexpr int LDT = 72;
  __shared__ __align__(16) bf16 Vt[2][64 * LDT];
  const int tid = threadIdx.x;
  const int w = tid >> 6, lane = tid & 63, quad = lane >> 4, l16 = lane & 15;
  const int pid = blockIdx.x;   // 0..15
  const int hh = blockIdx.y;    // 0..31
  const int n = hh >> 4, h = hh & 15;
  const int hb = n * QKVLD + h * Dd;
  const bf16* Qp = QKV + hb;
  const bf16* Kp = QKV + hb + E;
  const bf16* Vp = QKV + hb + 2 * E;

  const int vrow0 = tid >> 3, vd0 = (tid & 7) * 8;
  const int vrow1 = (tid + 256) >> 3, vd1 = (tid & 7) * 8;

  for (int half = 0; half < 2; ++half) {
    const int qt = (half == 0) ? (31 - pid) : pid;
    __syncthreads();  // protect Vt reuse across halves

    const int ql = qt * 64 + w * 16 + l16;  // this lane's q (sequence pos)
    const bf16x8 aq0 = ld8(Qp + (size_t)ql * LDL + quad * 8);
    const bf16x8 aq1 = ld8(Qp + (size_t)ql * LDL + 32 + quad * 8);

    f32x4 o_acc[4];
#pragma unroll
    for (int d = 0; d < 4; d++)
#pragma unroll
      for (int r = 0; r < 4; r++) o_acc[d][r] = 0.f;
    float m_run = -1e30f, l_run = 0.f;

    bf16x8 kc[4][2];
    uint4 vc0, vc1;
#pragma unroll
    for (int ks = 0; ks < 4; ks++)
#pragma unroll
      for (int c = 0; c < 2; c++)
        kc[ks][c] = ld8(Kp + (size_t)(ks * 16 + l16) * LDL + c * 32 + quad * 8);
    vc0 = *(const uint4*)(Vp + (size_t)vrow0 * LDL + vd0);
    vc1 = *(const uint4*)(Vp + (size_t)vrow1 * LDL + vd1);

    for (int kt = 0; kt <= qt; ++kt) {
      bf16* vb = Vt[kt & 1];
      {
        const bf16* t0 = (const bf16*)&vc0;
        const bf16* t1 = (const bf16*)&vc1;
#pragma unroll
        for (int i = 0; i < 8; i++) vb[(vd0 + i) * LDT + vrow0] = t0[i];
#pragma unroll
        for (int i = 0; i < 8; i++) vb[(vd1 + i) * LDT + vrow1] = t1[i];
      }
      __syncthreads();

      f32x4 s[4];
#pragma unroll
      for (int ks = 0; ks < 4; ks++) {
#pragma unroll
        for (int r = 0; r < 4; r++) s[ks][r] = 0.f;
        s[ks] = __builtin_amdgcn_mfma_f32_16x16x32_bf16(kc[ks][0], aq0, s[ks], 0, 0, 0);
        s[ks] = __builtin_amdgcn_mfma_f32_16x16x32_bf16(kc[ks][1], aq1, s[ks], 0, 0, 0);
      }

      if (kt < qt) {
        const size_t kb = (size_t)(kt + 1) * 64;
#pragma unroll
        for (int ks = 0; ks < 4; ks++)
#pragma unroll
          for (int c = 0; c < 2; c++)
            kc[ks][c] = ld8(Kp + (kb + ks * 16 + l16) * LDL + c * 32 + quad * 8);
        vc0 = *(const uint4*)(Vp + (kb + vrow0) * LDL + vd0);
        vc1 = *(const uint4*)(Vp + (kb + vrow1) * LDL + vd1);
      }

      if (kt == qt) {
#pragma unroll
        for (int ks = 0; ks < 4; ks++) {
#pragma unroll
          for (int r = 0; r < 4; r++) {
            const int kg = kt * 64 + ks * 16 + quad * 4 + r;
            if (kg > ql) s[ks][r] = -10000.0f;
          }
        }
      }

      float tmax = s[0][0];
#pragma unroll
      for (int ks = 0; ks < 4; ks++)
#pragma unroll
        for (int r = 0; r < 4; r++) tmax = fmaxf(tmax, s[ks][r]);
      tmax = fmaxf(tmax, __shfl_xor(tmax, 16, 64));
      tmax = fmaxf(tmax, __shfl_xor(tmax, 32, 64));
      const float mnew = fmaxf(m_run, tmax);
      const float alpha = __expf(m_run - mnew);
      m_run = mnew;
      float rsum = 0.f;
      short4v pf[4];
#pragma unroll
      for (int ks = 0; ks < 4; ks++) {
#pragma unroll
        for (int r = 0; r < 4; r++) {
          const float pv = __expf(s[ks][r] - mnew);
          rsum += pv;
          pf[ks][r] = bfbits(pv);
        }
      }
      rsum += __shfl_xor(rsum, 16, 64);
      rsum += __shfl_xor(rsum, 32, 64);
      l_run = l_run * alpha + rsum;
#pragma unroll
      for (int d = 0; d < 4; d++)
#pragma unroll
        for (int r = 0; r < 4; r++) o_acc[d][r] *= alpha;

#pragma unroll
      for (int d = 0; d < 4; d++) {
#pragma unroll
        for (int ks = 0; ks < 4; ks++) {
          const short4v av =
              *(const short4v*)&vb[(d * 16 + l16) * LDT + ks * 16 + quad * 4];
          o_acc[d] = __builtin_amdgcn_mfma_f32_16x16x16bf16_1k(av, pf[ks], o_acc[d], 0, 0, 0);
        }
      }
    }

    const float inv_l = 1.f / fmaxf(l_run, 1e-20f);
    const size_t obase = (size_t)ql * (Nb * E) + (size_t)n * E + h * Dd;
#pragma unroll
    for (int d = 0; d < 4; d++)
#pragma unroll
      for (int r = 0; r < 4; r++)
        O[obase + d * 16 + quad * 4 + r] = __float2bfloat16(o_acc[d][r] * inv_l);
  }
}

// ---------------------------------------------------------------------------
extern "C" void kernel_launch(void* const* d_in, const int* in_sizes, int n_in,
                              void* d_out, int out_size, void* d_ws, size_t ws_size,
                              hipStream_t stream) {
  const float* x    = (const float*)d_in[0];
  const float* ln1w = (const float*)d_in[1];
  const float* ln1b = (const float*)d_in[2];
  const float* wq   = (const float*)d_in[3];
  const float* bq   = (const float*)d_in[4];
  const float* wk   = (const float*)d_in[5];
  const float* bk   = (const float*)d_in[6];
  const float* wv   = (const float*)d_in[7];
  const float* bv   = (const float*)d_in[8];
  const float* wout = (const float*)d_in[9];
  const float* bout = (const float*)d_in[10];
  const float* ln2w = (const float*)d_in[11];
  const float* ln2b = (const float*)d_in[12];
  const float* fc1w = (const float*)d_in[13];
  const float* fc1b = (const float*)d_in[14];
  const float* fc2w = (const float*)d_in[15];
  const float* fc2b = (const float*)d_in[16];

  char* ws = (char*)d_ws;
  bf16* wqkvb = (bf16*)(ws);                        // 0-6 MB  [wq;wk;wv]
  bf16* woutb = (bf16*)(ws + ((size_t)6 << 20));    // 6-8 MB
  bf16* f1wb  = (bf16*)(ws + ((size_t)8 << 20));    // 8-16 MB
  bf16* P01   = (bf16*)(ws);                        // 0-16 MB: FC2 split-K
                                                    // partials (weights dead)
  bf16* f2wb  = (bf16*)(ws + ((size_t)16 << 20));   // 16-24 MB (live at FC2!)
  bf16* h1    = (bf16*)(ws + ((size_t)24 << 20));   // 24-32 MB (h2 reuses)
  bf16* qkv   = (bf16*)(ws + ((size_t)32 << 20));   // 32-56 MB [4096][3072]
  bf16* o     = (bf16*)(ws + ((size_t)56 << 20));   // 56-64 MB
  float* x1   = (float*)(ws + ((size_t)64 << 20));  // 64-80 MB f32
  bf16* f1    = (bf16*)(ws + ((size_t)32 << 20));   // 32-64 MB (reuses qkv,o)
  bf16* h2    = h1;
  float* outp = (float*)d_out;

  cvt_all_kernel<<<12288, 256, 0, stream>>>(wq, wk, wv, wout, fc1w, fc2w,
                                            wqkvb, woutb, f1wb, f2wb);

  ln_kernel<<<MT, 256, 0, stream>>>(x, ln1w, ln1b, h1);

  dim3 gQKV(QKVLD / 128, MT / 128);  // (24,32)
  dim3 gE(E / 128, MT / 128);        // (8,32)
  dim3 gF(Ff / 128, MT / 128);       // (32,32)
  dim3 gFC2(E / 128, MT / 128, 2);   // (8,32,2) split-K

  gemm_bt<0><<<gQKV, 256, 0, stream>>>(h1, wqkvb, bq, bk, bv, E, E, QKVLD,
                                       0.125f, 1024, nullptr, qkv, nullptr);

  attn_kernel<<<dim3(16, Nb * Hh), 256, 0, stream>>>(qkv, o);

  gemm_bt<1><<<gE, 256, 0, stream>>>(o, woutb, bout, nullptr, nullptr, E, E, E,
                                     1.f, 0, x, nullptr, x1);
  ln_kernel<<<MT, 256, 0, stream>>>(x1, ln2w, ln2b, h2);
  gemm_bt<2><<<gF, 256, 0, stream>>>(h2, f1wb, fc1b, nullptr, nullptr, E, E, Ff,
                                     1.f, 0, nullptr, f1, nullptr);
  gemm_bt<3><<<gFC2, 256, 0, stream>>>(f1, f2wb, nullptr, nullptr, nullptr,
                                       Ff / 2, Ff, E, 1.f, 0, nullptr, P01, nullptr);
  reduce2_kernel<<<MT * E / 4 / 256, 256, 0, stream>>>(P01, fc2b, x1, outp);
}